// Round 1
// baseline (568.525 us; speedup 1.0000x reference)
//
#include <hip/hip_runtime.h>

#define NEG_SLOPE 0.01f

// ---------------------------------------------------------------------------
// deg[i] = 1 (self-loop)
__global__ __launch_bounds__(256) void k_deg_init(float* __restrict__ deg, int n) {
    int i = blockIdx.x * 256 + threadIdx.x;
    if (i < n) deg[i] = 1.0f;
}

// deg[dst[e]] += 1
__global__ __launch_bounds__(256) void k_deg_count(const int* __restrict__ dst,
                                                   float* __restrict__ deg, int E) {
    int e = blockIdx.x * 256 + threadIdx.x;
    if (e < E) unsafeAtomicAdd(&deg[dst[e]], 1.0f);
}

// deg -> rsqrt(deg), in place. deg > 0 always (self-loops).
__global__ __launch_bounds__(256) void k_dinv(float* __restrict__ deg, int n) {
    int i = blockIdx.x * 256 + threadIdx.x;
    if (i < n) deg[i] = rsqrtf(deg[i]);
}

// y[i][j] = dinv[i] * sum_k x[i][k]*W[k][j];  agg[i][j] = y[i][j]  (self-loop init)
// 256 threads / block, 4 rows per block, 64 cols.
template <int K>
__global__ __launch_bounds__(256) void k_gemm(const float* __restrict__ x,
                                              const float* __restrict__ W,
                                              const float* __restrict__ dinv,
                                              float* __restrict__ y,
                                              float* __restrict__ agg, int n) {
    __shared__ float ws[K * 64];
    __shared__ float xs[4][K];
    for (int t = threadIdx.x; t < K * 64; t += 256) ws[t] = W[t];
    int row0 = blockIdx.x * 4;
    for (int t = threadIdx.x; t < 4 * K; t += 256) {
        int r = t / K, k = t - r * K;
        int row = row0 + r;
        xs[r][k] = (row < n) ? x[row * K + k] : 0.0f;
    }
    __syncthreads();
    int r = threadIdx.x >> 6;
    int c = threadIdx.x & 63;
    int i = row0 + r;
    if (i >= n) return;
    float sum = 0.0f;
#pragma unroll
    for (int k = 0; k < K; ++k) sum += xs[r][k] * ws[k * 64 + c];
    float v = dinv[i] * sum;
    y[i * 64 + c]   = v;
    agg[i * 64 + c] = v;
}

// agg[dst[e]][f] += y[src[e]][f]   — one thread per (edge, feature)
__global__ __launch_bounds__(256) void k_scatter(const int* __restrict__ src,
                                                 const int* __restrict__ dst,
                                                 const float* __restrict__ y,
                                                 float* __restrict__ agg, int E) {
    int idx = blockIdx.x * 256 + threadIdx.x;
    int e = idx >> 6;
    if (e >= E) return;
    int f = idx & 63;
    float v = y[src[e] * 64 + f];
    unsafeAtomicAdd(&agg[dst[e] * 64 + f], v);
}

// out[i][j] = dinv[i]*agg[i][j] + b[j]   (+ leaky relu), in place
template <bool RELU>
__global__ __launch_bounds__(256) void k_epilogue(float* __restrict__ agg,
                                                  const float* __restrict__ dinv,
                                                  const float* __restrict__ b, int n) {
    int idx = blockIdx.x * 256 + threadIdx.x;
    if (idx >= n * 64) return;
    int i = idx >> 6;
    int j = idx & 63;
    float v = dinv[i] * agg[idx] + b[j];
    if (RELU) v = (v > 0.0f) ? v : NEG_SLOPE * v;
    agg[idx] = v;
}

extern "C" void kernel_launch(void* const* d_in, const int* in_sizes, int n_in,
                              void* d_out, int out_size, void* d_ws, size_t ws_size,
                              hipStream_t stream) {
    const float* x  = (const float*)d_in[0];
    const int*   ei = (const int*)d_in[1];
    const float* W1 = (const float*)d_in[2];
    const float* b1 = (const float*)d_in[3];
    const float* W2 = (const float*)d_in[4];
    const float* b2 = (const float*)d_in[5];
    float* out = (float*)d_out;

    const int N = in_sizes[0] / 128;   // 50000
    const int E = in_sizes[1] / 2;     // 800000
    const int* src = ei;
    const int* dst = ei + E;

    // workspace layout
    char* w = (char*)d_ws;
    float* dinv = (float*)w;                              // N floats (deg, then rsqrt in place)
    size_t off = ((size_t)N * 4 + 255) & ~(size_t)255;
    float* y   = (float*)(w + off);                       // N*64 floats
    float* agg = y + (size_t)N * 64;                      // N*64 floats

    const int nb_n   = (N + 255) / 256;
    const int nb_e   = (E + 255) / 256;
    const int nb_nf  = (N * 64 + 255) / 256;
    const int nb_ef  = (int)(((long long)E * 64 + 255) / 256);
    const int nb_row = (N + 3) / 4;

    // ---- degree / normalization ----
    k_deg_init<<<nb_n, 256, 0, stream>>>(dinv, N);
    k_deg_count<<<nb_e, 256, 0, stream>>>(dst, dinv, E);
    k_dinv<<<nb_n, 256, 0, stream>>>(dinv, N);

    // ---- layer 1 ----
    k_gemm<128><<<nb_row, 256, 0, stream>>>(x, W1, dinv, y, agg, N);
    k_scatter<<<nb_ef, 256, 0, stream>>>(src, dst, y, agg, E);
    k_epilogue<true><<<nb_nf, 256, 0, stream>>>(agg, dinv, b1, N);   // agg now holds h

    // ---- layer 2 ----
    k_gemm<64><<<nb_row, 256, 0, stream>>>(agg, W2, dinv, y, out, N);
    k_scatter<<<nb_ef, 256, 0, stream>>>(src, dst, y, out, E);
    k_epilogue<false><<<nb_nf, 256, 0, stream>>>(out, dinv, b2, N);
}

// Round 3
// 323.514 us; speedup vs baseline: 1.7573x; 1.7573x over previous
//
#include <hip/hip_runtime.h>

#define NEG_SLOPE 0.01f

// ---------------------------------------------------------------------------
// zero an int array
__global__ __launch_bounds__(256) void k_zero(int* __restrict__ p, int n) {
    int i = blockIdx.x * 256 + threadIdx.x;
    if (i < n) p[i] = 0;
}

// cnt[dst[e]] += 1  (int atomics, in-degree excluding self-loop)
__global__ __launch_bounds__(256) void k_hist(const int* __restrict__ dst,
                                              int* __restrict__ cnt, int E) {
    int e = blockIdx.x * 256 + threadIdx.x;
    if (e < E) atomicAdd(&cnt[dst[e]], 1);
}

// dinv[i] = rsqrt(1 + cnt[i])   (self-loop included)
__global__ __launch_bounds__(256) void k_dinv(const int* __restrict__ cnt,
                                              float* __restrict__ dinv, int n) {
    int i = blockIdx.x * 256 + threadIdx.x;
    if (i < n) dinv[i] = rsqrtf(1.0f + (float)cnt[i]);
}

// ---- 3-kernel inclusive scan over cnt -> row_ptr -------------------------
__global__ __launch_bounds__(256) void k_scan1(const int* __restrict__ cnt,
                                               int* __restrict__ incl,
                                               int* __restrict__ bsum, int n) {
    __shared__ int sm[256];
    int i = blockIdx.x * 256 + threadIdx.x;
    int t = threadIdx.x;
    sm[t] = (i < n) ? cnt[i] : 0;
    __syncthreads();
    for (int ofs = 1; ofs < 256; ofs <<= 1) {
        int v = (t >= ofs) ? sm[t - ofs] : 0;
        __syncthreads();
        sm[t] += v;
        __syncthreads();
    }
    if (i < n) incl[i] = sm[t];
    if (t == 255) bsum[blockIdx.x] = sm[255];
}

__global__ __launch_bounds__(256) void k_scan2(int* __restrict__ bsum, int nb) {
    __shared__ int sm[256];
    int t = threadIdx.x;
    sm[t] = (t < nb) ? bsum[t] : 0;
    __syncthreads();
    for (int ofs = 1; ofs < 256; ofs <<= 1) {
        int v = (t >= ofs) ? sm[t - ofs] : 0;
        __syncthreads();
        sm[t] += v;
        __syncthreads();
    }
    if (t < nb) bsum[t] = sm[t];  // inclusive block sums
}

// row_ptr[i+1] = incl[i] + sum of previous blocks; row_ptr[0] = 0; fill[i] = 0
__global__ __launch_bounds__(256) void k_scan3(const int* __restrict__ incl,
                                               const int* __restrict__ bsum,
                                               int* __restrict__ row_ptr,
                                               int* __restrict__ fill, int n) {
    int i = blockIdx.x * 256 + threadIdx.x;
    if (i < n) {
        int off = (blockIdx.x > 0) ? bsum[blockIdx.x - 1] : 0;
        row_ptr[i + 1] = incl[i] + off;
        fill[i] = 0;
    }
    if (i == 0) row_ptr[0] = 0;
}

// counting-sort permute: ssrc[row_ptr[d] + fill[d]++] = src[e]
__global__ __launch_bounds__(256) void k_fill(const int* __restrict__ src,
                                              const int* __restrict__ dst,
                                              const int* __restrict__ row_ptr,
                                              int* __restrict__ fill,
                                              int* __restrict__ ssrc, int E) {
    int e = blockIdx.x * 256 + threadIdx.x;
    if (e >= E) return;
    int d = dst[e];
    int pos = row_ptr[d] + atomicAdd(&fill[d], 1);
    ssrc[pos] = src[e];
}

// ---------------------------------------------------------------------------
// y[i][c] = dinv[i] * sum_k x[i][k] * W[k][c]
// 32 rows / block, 4 waves, each wave computes 8 rows x 64 cols.
template <int K>
__global__ __launch_bounds__(256) void k_gemm(const float* __restrict__ x,
                                              const float* __restrict__ W,
                                              const float* __restrict__ dinv,
                                              float* __restrict__ y, int n) {
    __shared__ float ws[K * 64];
    __shared__ float xs[32][K];
    const int tid = threadIdx.x;
    for (int t = tid; t < K * 16; t += 256)
        ((float4*)ws)[t] = ((const float4*)W)[t];
    const int row0 = blockIdx.x * 32;
    for (int t = tid; t < 8 * K; t += 256) {   // 32*K/4 float4 elements
        int r  = t / (K / 4);
        int kk = t - r * (K / 4);
        int row = row0 + r;
        float4 v = (row < n) ? ((const float4*)(x + (size_t)row * K))[kk]
                             : make_float4(0.f, 0.f, 0.f, 0.f);
        ((float4*)&xs[r][0])[kk] = v;
    }
    __syncthreads();
    const int wave  = tid >> 6;
    const int c     = tid & 63;
    const int rbase = wave * 8;
    float acc[8] = {};
#pragma unroll 4
    for (int k = 0; k < K; ++k) {
        float wv = ws[k * 64 + c];
#pragma unroll
        for (int r = 0; r < 8; ++r) acc[r] += xs[rbase + r][k] * wv;
    }
#pragma unroll
    for (int r = 0; r < 8; ++r) {
        int row = row0 + rbase + r;
        if (row < n) y[(size_t)row * 64 + c] = dinv[row] * acc[r];
    }
}

// ---------------------------------------------------------------------------
// out[i][c] = act( dinv[i] * ( y[i][c] + sum_{e in CSR[i]} y[ssrc[e]][c] ) + b[c] )
// one wave per node, lane = feature.
template <bool RELU>
__global__ __launch_bounds__(256) void k_gather(const int* __restrict__ row_ptr,
                                                const int* __restrict__ ssrc,
                                                const float* __restrict__ y,
                                                const float* __restrict__ dinv,
                                                const float* __restrict__ b,
                                                float* __restrict__ out, int n) {
    int node = blockIdx.x * 4 + (threadIdx.x >> 6);
    if (node >= n) return;
    int lane = threadIdx.x & 63;
    float acc = y[(size_t)node * 64 + lane];   // self-loop term
    int beg = row_ptr[node], end = row_ptr[node + 1];
    for (int base = beg; base < end; base += 64) {
        int m = end - base;
        if (m > 64) m = 64;
        int idx = (lane < m) ? ssrc[base + lane] : 0;
        for (int j = 0; j < m; ++j) {
            int s = __shfl(idx, j);
            acc += y[(size_t)s * 64 + lane];
        }
    }
    float v = dinv[node] * acc + b[lane];
    if (RELU) v = (v > 0.f) ? v : NEG_SLOPE * v;
    out[(size_t)node * 64 + lane] = v;
}

// ---------------------------------------------------------------------------
extern "C" void kernel_launch(void* const* d_in, const int* in_sizes, int n_in,
                              void* d_out, int out_size, void* d_ws, size_t ws_size,
                              hipStream_t stream) {
    const float* x  = (const float*)d_in[0];
    const int*   ei = (const int*)d_in[1];
    const float* W1 = (const float*)d_in[2];
    const float* b1 = (const float*)d_in[3];
    const float* W2 = (const float*)d_in[4];
    const float* b2 = (const float*)d_in[5];
    float* out = (float*)d_out;

    const int N = in_sizes[0] / 128;   // 50000
    const int E = in_sizes[1] / 2;     // 800000
    const int* src = ei;
    const int* dst = ei + E;

    // ---- workspace layout (256B aligned blocks) ----
    auto align = [](size_t v) { return (v + 255) & ~(size_t)255; };
    char* w = (char*)d_ws;
    size_t o = 0;
    int*   cnt     = (int*)(w + o);  o += align((size_t)N * 4);
    int*   fill    = (int*)(w + o);  o += align((size_t)N * 4);
    int*   incl    = (int*)(w + o);  o += align((size_t)N * 4);
    int*   bsum    = (int*)(w + o);  o += align(256 * 4);
    int*   row_ptr = (int*)(w + o);  o += align((size_t)(N + 1) * 4);
    float* dinv    = (float*)(w + o); o += align((size_t)N * 4);
    int*   ssrc    = (int*)(w + o);  o += align((size_t)E * 4);
    float* y       = (float*)(w + o); o += align((size_t)N * 64 * 4);
    float* h       = out;            // d_out doubles as layer-1 activation buffer

    const int nb_n = (N + 255) / 256;
    const int nb_e = (E + 255) / 256;
    const int nb_s = (N + 255) / 256;          // scan blocks (196 <= 256)
    const int nb_g = (N + 31) / 32;            // gemm blocks
    const int nb_a = (N + 3) / 4;              // gather blocks

    // ---- preprocessing: degrees + CSR by dst ----
    k_zero <<<nb_n, 256, 0, stream>>>(cnt, N);
    k_hist <<<nb_e, 256, 0, stream>>>(dst, cnt, E);
    k_dinv <<<nb_n, 256, 0, stream>>>(cnt, dinv, N);
    k_scan1<<<nb_s, 256, 0, stream>>>(cnt, incl, bsum, N);
    k_scan2<<<1,    256, 0, stream>>>(bsum, nb_s);
    k_scan3<<<nb_s, 256, 0, stream>>>(incl, bsum, row_ptr, fill, N);
    k_fill <<<nb_e, 256, 0, stream>>>(src, dst, row_ptr, fill, ssrc, E);

    // ---- layer 1 ----
    k_gemm<128><<<nb_g, 256, 0, stream>>>(x, W1, dinv, y, N);
    k_gather<true><<<nb_a, 256, 0, stream>>>(row_ptr, ssrc, y, dinv, b1, h, N);

    // ---- layer 2 ----
    k_gemm<64><<<nb_g, 256, 0, stream>>>(h, W2, dinv, y, N);
    k_gather<false><<<nb_a, 256, 0, stream>>>(row_ptr, ssrc, y, dinv, b2, out, N);
}

// Round 8
// 263.515 us; speedup vs baseline: 2.1575x; 1.2277x over previous
//
#include <hip/hip_runtime.h>

#define NEG_SLOPE 0.01f

__device__ __forceinline__ void f4add(float4& a, const float4& v) {
    a.x += v.x; a.y += v.y; a.z += v.z; a.w += v.w;
}

// ---------------------------------------------------------------------------
__global__ __launch_bounds__(256) void k_zero(int* __restrict__ p, int n) {
    int i = blockIdx.x * 256 + threadIdx.x;
    if (i < n) p[i] = 0;
}

// cnt[dst[e]] += 1
__global__ __launch_bounds__(256) void k_hist(const int* __restrict__ dst,
                                              int* __restrict__ cnt, int E) {
    int e = blockIdx.x * 256 + threadIdx.x;
    if (e < E) atomicAdd(&cnt[dst[e]], 1);
}

// ---- scan over cnt -> row_ptr; also dinv = rsqrt(1+cnt) -------------------
__global__ __launch_bounds__(256) void k_scan1(const int* __restrict__ cnt,
                                               int* __restrict__ incl,
                                               int* __restrict__ bsum,
                                               float* __restrict__ dinv, int n) {
    __shared__ int sm[256];
    int i = blockIdx.x * 256 + threadIdx.x;
    int t = threadIdx.x;
    int c = (i < n) ? cnt[i] : 0;
    if (i < n) dinv[i] = rsqrtf(1.0f + (float)c);
    sm[t] = c;
    __syncthreads();
    for (int ofs = 1; ofs < 256; ofs <<= 1) {
        int v = (t >= ofs) ? sm[t - ofs] : 0;
        __syncthreads();
        sm[t] += v;
        __syncthreads();
    }
    if (i < n) incl[i] = sm[t];
    if (t == 255) bsum[blockIdx.x] = sm[255];
}

__global__ __launch_bounds__(256) void k_scan2(int* __restrict__ bsum, int nb) {
    __shared__ int sm[256];
    int t = threadIdx.x;
    sm[t] = (t < nb) ? bsum[t] : 0;
    __syncthreads();
    for (int ofs = 1; ofs < 256; ofs <<= 1) {
        int v = (t >= ofs) ? sm[t - ofs] : 0;
        __syncthreads();
        sm[t] += v;
        __syncthreads();
    }
    if (t < nb) bsum[t] = sm[t];
}

__global__ __launch_bounds__(256) void k_scan3(const int* __restrict__ incl,
                                               const int* __restrict__ bsum,
                                               int* __restrict__ row_ptr,
                                               int* __restrict__ fill, int n) {
    int i = blockIdx.x * 256 + threadIdx.x;
    if (i < n) {
        int off = (blockIdx.x > 0) ? bsum[blockIdx.x - 1] : 0;
        row_ptr[i + 1] = incl[i] + off;
        fill[i] = 0;
    }
    if (i == 0) row_ptr[0] = 0;
}

// ---------------------------------------------------------------------------
// Fused: blocks [0, nbe) do the CSR permute (latency-bound), blocks
// [nbe, nbe+nbg) do layer-1 GEMM (compute-bound). Independent work overlapped
// in one dispatch.
__global__ __launch_bounds__(256) void k_gemm1_fill(
    const float* __restrict__ x, const float* __restrict__ W,
    const float* __restrict__ dinv, float* __restrict__ y, int n,
    const int* __restrict__ src, const int* __restrict__ dst,
    const int* __restrict__ row_ptr, int* __restrict__ fill,
    int* __restrict__ ssrc, int E, int nbe) {
    constexpr int K = 128;
    if ((int)blockIdx.x < nbe) {
        int e = blockIdx.x * 256 + threadIdx.x;
        if (e < E) {
            int d = dst[e];
            int pos = row_ptr[d] + atomicAdd(&fill[d], 1);
            ssrc[pos] = src[e];
        }
        return;
    }
    __shared__ float ws[K * 64];
    __shared__ float xs[32][K];
    const int tid = threadIdx.x;
    for (int t = tid; t < K * 16; t += 256)
        ((float4*)ws)[t] = ((const float4*)W)[t];
    const int row0 = (blockIdx.x - nbe) * 32;
    for (int t = tid; t < 8 * K; t += 256) {
        int r  = t / (K / 4);
        int kk = t - r * (K / 4);
        int row = row0 + r;
        float4 v = (row < n) ? ((const float4*)(x + (size_t)row * K))[kk]
                             : make_float4(0.f, 0.f, 0.f, 0.f);
        ((float4*)&xs[r][0])[kk] = v;
    }
    __syncthreads();
    const int wave  = tid >> 6;
    const int c     = tid & 63;
    const int rbase = wave * 8;
    float acc[8] = {};
#pragma unroll 4
    for (int k = 0; k < K; ++k) {
        float wv = ws[k * 64 + c];
#pragma unroll
        for (int r = 0; r < 8; ++r) acc[r] += xs[rbase + r][k] * wv;
    }
#pragma unroll
    for (int r = 0; r < 8; ++r) {
        int row = row0 + rbase + r;
        if (row < n) y[(size_t)row * 64 + c] = dinv[row] * acc[r];
    }
}

// standalone GEMM for layer 2 (K=64)
__global__ __launch_bounds__(256) void k_gemm64(const float* __restrict__ x,
                                                const float* __restrict__ W,
                                                const float* __restrict__ dinv,
                                                float* __restrict__ y, int n) {
    constexpr int K = 64;
    __shared__ float ws[K * 64];
    __shared__ float xs[32][K];
    const int tid = threadIdx.x;
    for (int t = tid; t < K * 16; t += 256)
        ((float4*)ws)[t] = ((const float4*)W)[t];
    const int row0 = blockIdx.x * 32;
    for (int t = tid; t < 8 * K; t += 256) {
        int r  = t / (K / 4);
        int kk = t - r * (K / 4);
        int row = row0 + r;
        float4 v = (row < n) ? ((const float4*)(x + (size_t)row * K))[kk]
                             : make_float4(0.f, 0.f, 0.f, 0.f);
        ((float4*)&xs[r][0])[kk] = v;
    }
    __syncthreads();
    const int wave  = tid >> 6;
    const int c     = tid & 63;
    const int rbase = wave * 8;
    float acc[8] = {};
#pragma unroll 4
    for (int k = 0; k < K; ++k) {
        float wv = ws[k * 64 + c];
#pragma unroll
        for (int r = 0; r < 8; ++r) acc[r] += xs[rbase + r][k] * wv;
    }
#pragma unroll
    for (int r = 0; r < 8; ++r) {
        int row = row0 + rbase + r;
        if (row < n) y[(size_t)row * 64 + c] = dinv[row] * acc[r];
    }
}

// ---------------------------------------------------------------------------
// Gather: 16 lanes x float4 per node, 16 nodes per block. Each quarter-wave
// walks its node's in-edge list; 4-way unroll + 4 accumulators for MLP.
template <bool RELU>
__global__ __launch_bounds__(256) void k_gather(const int* __restrict__ row_ptr,
                                                const int* __restrict__ ssrc,
                                                const float* __restrict__ y,
                                                const float* __restrict__ dinv,
                                                const float* __restrict__ b,
                                                float* __restrict__ out, int n) {
    int node = blockIdx.x * 16 + (threadIdx.x >> 4);
    if (node >= n) return;
    int sub = threadIdx.x & 15;
    const float4* Y4 = (const float4*)y;
    float4 a0 = Y4[(size_t)node * 16 + sub];  // self-loop term
    float4 a1 = make_float4(0.f, 0.f, 0.f, 0.f);
    float4 a2 = make_float4(0.f, 0.f, 0.f, 0.f);
    float4 a3 = make_float4(0.f, 0.f, 0.f, 0.f);
    int j = row_ptr[node];
    const int end = row_ptr[node + 1];
    for (; j + 4 <= end; j += 4) {
        int s0 = ssrc[j], s1 = ssrc[j + 1], s2 = ssrc[j + 2], s3 = ssrc[j + 3];
        float4 v0 = Y4[(size_t)s0 * 16 + sub];
        float4 v1 = Y4[(size_t)s1 * 16 + sub];
        float4 v2 = Y4[(size_t)s2 * 16 + sub];
        float4 v3 = Y4[(size_t)s3 * 16 + sub];
        f4add(a0, v0); f4add(a1, v1); f4add(a2, v2); f4add(a3, v3);
    }
    for (; j < end; ++j) {
        int s = ssrc[j];
        float4 v = Y4[(size_t)s * 16 + sub];
        f4add(a1, v);
    }
    f4add(a0, a1); f4add(a2, a3); f4add(a0, a2);
    float di = dinv[node];
    float4 bb = ((const float4*)b)[sub];
    float4 r;
    r.x = di * a0.x + bb.x;
    r.y = di * a0.y + bb.y;
    r.z = di * a0.z + bb.z;
    r.w = di * a0.w + bb.w;
    if (RELU) {
        r.x = (r.x > 0.f) ? r.x : NEG_SLOPE * r.x;
        r.y = (r.y > 0.f) ? r.y : NEG_SLOPE * r.y;
        r.z = (r.z > 0.f) ? r.z : NEG_SLOPE * r.z;
        r.w = (r.w > 0.f) ? r.w : NEG_SLOPE * r.w;
    }
    ((float4*)out)[(size_t)node * 16 + sub] = r;
}

// ---------------------------------------------------------------------------
extern "C" void kernel_launch(void* const* d_in, const int* in_sizes, int n_in,
                              void* d_out, int out_size, void* d_ws, size_t ws_size,
                              hipStream_t stream) {
    const float* x  = (const float*)d_in[0];
    const int*   ei = (const int*)d_in[1];
    const float* W1 = (const float*)d_in[2];
    const float* b1 = (const float*)d_in[3];
    const float* W2 = (const float*)d_in[4];
    const float* b2 = (const float*)d_in[5];
    float* out = (float*)d_out;

    const int N = in_sizes[0] / 128;   // 50000
    const int E = in_sizes[1] / 2;     // 800000
    const int* src = ei;
    const int* dst = ei + E;

    auto align = [](size_t v) { return (v + 255) & ~(size_t)255; };
    char* w = (char*)d_ws;
    size_t o = 0;
    int*   cnt     = (int*)(w + o);  o += align((size_t)N * 4);
    int*   fill    = (int*)(w + o);  o += align((size_t)N * 4);
    int*   incl    = (int*)(w + o);  o += align((size_t)N * 4);
    int*   bsum    = (int*)(w + o);  o += align(256 * 4);
    int*   row_ptr = (int*)(w + o);  o += align((size_t)(N + 1) * 4);
    float* dinv    = (float*)(w + o); o += align((size_t)N * 4);
    int*   ssrc    = (int*)(w + o);  o += align((size_t)E * 4);
    float* y       = (float*)(w + o); o += align((size_t)N * 64 * 4);
    float* h       = out;            // d_out doubles as layer-1 activation

    const int nb_n  = (N + 255) / 256;
    const int nb_e  = (E + 255) / 256;
    const int nb_g  = (N + 31) / 32;
    const int nb_a  = (N + 15) / 16;

    // ---- preprocessing ----
    k_zero <<<nb_n, 256, 0, stream>>>(cnt, N);
    k_hist <<<nb_e, 256, 0, stream>>>(dst, cnt, E);
    k_scan1<<<nb_n, 256, 0, stream>>>(cnt, incl, bsum, dinv, N);
    k_scan2<<<1,    256, 0, stream>>>(bsum, nb_n);
    k_scan3<<<nb_n, 256, 0, stream>>>(incl, bsum, row_ptr, fill, N);

    // ---- layer 1 (CSR fill overlapped with GEMM) ----
    k_gemm1_fill<<<nb_e + nb_g, 256, 0, stream>>>(x, W1, dinv, y, N,
                                                  src, dst, row_ptr, fill, ssrc, E, nb_e);
    k_gather<true><<<nb_a, 256, 0, stream>>>(row_ptr, ssrc, y, dinv, b1, h, N);

    // ---- layer 2 ----
    k_gemm64<<<nb_g, 256, 0, stream>>>(h, W2, dinv, y, N);
    k_gather<false><<<nb_a, 256, 0, stream>>>(row_ptr, ssrc, y, dinv, b2, out, N);
}